// Round 6
// baseline (1847.601 us; speedup 1.0000x reference)
//
#include <hip/hip_runtime.h>

#define BB 64
#define SS 2048
#define II 128
#define HH 256
#define OO 128

// ---------------------------------------------------------------------------
// Prep: transpose W_ih -> [I][H], W_fc -> [H][O], combine biases.
// ---------------------------------------------------------------------------
__global__ void prep_kernel(const float* __restrict__ W_ih, const float* __restrict__ b_ih,
                            const float* __restrict__ b_hh, const float* __restrict__ W_fc,
                            float* __restrict__ wihT, float* __restrict__ wfcT,
                            float* __restrict__ biasc) {
    int idx = blockIdx.x * 256 + threadIdx.x;
    if (idx < HH * II) {            // W_ih [H][I] -> wihT [I][H]
        int j = idx / II, k = idx % II;
        wihT[k * HH + j] = W_ih[idx];
    }
    if (idx < OO * HH) {            // W_fc [O][H] -> wfcT [H][O]
        int j = idx / HH, k = idx % HH;
        wfcT[k * OO + j] = W_fc[idx];
    }
    if (idx < HH) biasc[idx] = b_ih[idx] + b_hh[idx];
}

// ---------------------------------------------------------------------------
// Generic row-major GEMM: C[r][j] = sum_k A[r][k] * Wt[k][j] + bias[j]
// 256 threads, 8x8 micro-tile per thread. (unchanged — scan dominates)
// ---------------------------------------------------------------------------
template<int KD, int JD, int RT>
__global__ __launch_bounds__(256, 2)
void gemm_rk(const float* __restrict__ A, const float* __restrict__ Wt,
             const float* __restrict__ bias, float* __restrict__ C) {
    constexpr int KT = 64;
    constexpr int TJ = JD / 8;      // threads along j
    constexpr int TR = RT / 8;      // threads along r  (TJ*TR == 256)
    static_assert(TJ * TR == 256, "bad tiling");

    __shared__ __align__(16) float a_lds[RT][KT];
    __shared__ __align__(16) float w_lds[KT][JD];

    const int tid = threadIdx.x;
    const int tj = tid % TJ;
    const int tr = tid / TJ;
    const long r0 = (long)blockIdx.x * RT;

    float acc[8][8];
#pragma unroll
    for (int r = 0; r < 8; ++r)
#pragma unroll
        for (int j = 0; j < 8; ++j) acc[r][j] = 0.0f;

    for (int kt = 0; kt < KD; kt += KT) {
        {
            constexpr int NF4 = RT * KT / 4;
#pragma unroll
            for (int f = 0; f < NF4 / 256; ++f) {
                int fl = f * 256 + tid;
                int rr = fl / (KT / 4), kk4 = fl % (KT / 4);
                *(float4*)&a_lds[rr][kk4 * 4] =
                    *(const float4*)&A[(r0 + rr) * KD + kt + kk4 * 4];
            }
        }
        {
            constexpr int NF4 = KT * JD / 4;
#pragma unroll
            for (int f = 0; f < NF4 / 256; ++f) {
                int fl = f * 256 + tid;
                int kk = fl / (JD / 4), jj4 = fl % (JD / 4);
                *(float4*)&w_lds[kk][jj4 * 4] =
                    *(const float4*)&Wt[(long)(kt + kk) * JD + jj4 * 4];
            }
        }
        __syncthreads();

#pragma unroll 4
        for (int k4 = 0; k4 < KT; k4 += 4) {
            float4 xv[8];
#pragma unroll
            for (int r = 0; r < 8; ++r)
                xv[r] = *(const float4*)&a_lds[tr * 8 + r][k4];
#pragma unroll
            for (int i = 0; i < 4; ++i) {
                float4 wa = *(const float4*)&w_lds[k4 + i][tj * 8];
                float4 wb = *(const float4*)&w_lds[k4 + i][tj * 8 + 4];
#pragma unroll
                for (int r = 0; r < 8; ++r) {
                    float xs = (i == 0) ? xv[r].x : (i == 1) ? xv[r].y
                             : (i == 2) ? xv[r].z : xv[r].w;
                    acc[r][0] = fmaf(xs, wa.x, acc[r][0]);
                    acc[r][1] = fmaf(xs, wa.y, acc[r][1]);
                    acc[r][2] = fmaf(xs, wa.z, acc[r][2]);
                    acc[r][3] = fmaf(xs, wa.w, acc[r][3]);
                    acc[r][4] = fmaf(xs, wb.x, acc[r][4]);
                    acc[r][5] = fmaf(xs, wb.y, acc[r][5]);
                    acc[r][6] = fmaf(xs, wb.z, acc[r][6]);
                    acc[r][7] = fmaf(xs, wb.w, acc[r][7]);
                }
            }
        }
        __syncthreads();
    }

    float4 b0 = *(const float4*)&bias[tj * 8];
    float4 b1 = *(const float4*)&bias[tj * 8 + 4];
#pragma unroll
    for (int r = 0; r < 8; ++r) {
        long row = r0 + tr * 8 + r;
        float4 o0, o1;
        o0.x = acc[r][0] + b0.x; o0.y = acc[r][1] + b0.y;
        o0.z = acc[r][2] + b0.z; o0.w = acc[r][3] + b0.w;
        o1.x = acc[r][4] + b1.x; o1.y = acc[r][5] + b1.y;
        o1.z = acc[r][6] + b1.z; o1.w = acc[r][7] + b1.w;
        *(float4*)&C[row * JD + tj * 8]     = o0;
        *(float4*)&C[row * JD + tj * 8 + 4] = o1;
    }
}

// ---------------------------------------------------------------------------
// Sequential scan v3: h_t = tanh(xp_t + h_{t-1} @ W_hh^T), in-place.
// 64 blocks (one per batch) x 1024 threads (16 waves, 4/SIMD).
// Thread (w, l): sl = l&15 -> output j = w*16+sl; q = l>>4 -> k-quarter
// [q*64, q*64+64). 64 weight floats per thread, PINNED in VGPRs via opaque
// asm (v1/v2 showed VGPR=84: the compiler was re-loading weights every step
// -> that was the real bottleneck). 64 FMAs on 4 ILP chains; butterfly
// shfl_xor(16,32) reduces the 4 quarters in-wave; all lanes compute tanh
// redundantly (same per-wave issue cost, no extra barrier); q==0 stores.
// h double-buffered in LDS, quarters staggered by 68 floats (bank offset
// q*4 -> the 4 distinct broadcast addresses per ds_read hit disjoint banks).
// ONE barrier per step.
// ---------------------------------------------------------------------------
__global__ __launch_bounds__(1024, 4)
void rnn_scan(const float* __restrict__ W_hh, float* __restrict__ hid) {
    const int b   = blockIdx.x;
    const int tid = threadIdx.x;
    const int w   = tid >> 6;        // wave 0..15
    const int l   = tid & 63;
    const int sl  = l & 15;
    const int q   = l >> 4;          // k-quarter 0..3

    const int j  = w * 16 + sl;      // this thread's output index
    const int k0 = q * 64;           // k range [k0, k0+64)

    __shared__ __align__(16) float h_lds[2][4 * 68];

    // 16 float4 = 64 weight floats: W_hh[j][k0 .. k0+63]
    float4 wv[16];
#pragma unroll
    for (int i = 0; i < 16; ++i)
        wv[i] = *(const float4*)&W_hh[(size_t)j * HH + k0 + i * 4];
    // Pin: opaque to the optimizer -> cannot rematerialize the loads inside
    // the loop; the 64 values must stay live in VGPRs.
#pragma unroll
    for (int i = 0; i < 16; ++i)
        asm volatile("" : "+v"(wv[i].x), "+v"(wv[i].y), "+v"(wv[i].z), "+v"(wv[i].w));

    for (int i = tid; i < 2 * 4 * 68; i += 1024) ((float*)h_lds)[i] = 0.0f;

    float* __restrict__ base = hid + (size_t)b * SS * HH;
    // xproj prefetch pipeline, depth 2 (all 4 quarter-lanes of a j load the
    // same address -> coalescer broadcast)
    float xp0 = base[j];
    float xp1 = base[HH + j];
    __syncthreads();

#pragma unroll 1
    for (int t = 0; t < SS; ++t) {
        float xp2 = (t + 2 < SS) ? base[(size_t)(t + 2) * HH + j] : 0.0f;

        const float4* hb = (const float4*)&h_lds[t & 1][q * 68];
        float a0 = 0.f, a1 = 0.f, a2 = 0.f, a3 = 0.f;
#pragma unroll
        for (int i = 0; i < 16; i += 4) {
            float4 h0 = hb[i], h1 = hb[i + 1], h2 = hb[i + 2], h3 = hb[i + 3];
            a0 = fmaf(h0.x, wv[i].x, a0);
            a0 = fmaf(h0.y, wv[i].y, a0);
            a0 = fmaf(h0.z, wv[i].z, a0);
            a0 = fmaf(h0.w, wv[i].w, a0);
            a1 = fmaf(h1.x, wv[i + 1].x, a1);
            a1 = fmaf(h1.y, wv[i + 1].y, a1);
            a1 = fmaf(h1.z, wv[i + 1].z, a1);
            a1 = fmaf(h1.w, wv[i + 1].w, a1);
            a2 = fmaf(h2.x, wv[i + 2].x, a2);
            a2 = fmaf(h2.y, wv[i + 2].y, a2);
            a2 = fmaf(h2.z, wv[i + 2].z, a2);
            a2 = fmaf(h2.w, wv[i + 2].w, a2);
            a3 = fmaf(h3.x, wv[i + 3].x, a3);
            a3 = fmaf(h3.y, wv[i + 3].y, a3);
            a3 = fmaf(h3.z, wv[i + 3].z, a3);
            a3 = fmaf(h3.w, wv[i + 3].w, a3);
        }
        float s = (a0 + a1) + (a2 + a3);
        // butterfly over the 4 k-quarters (lanes sl, sl+16, sl+32, sl+48);
        // afterwards ALL lanes hold the full dot for output j
        s += __shfl_xor(s, 16, 64);
        s += __shfl_xor(s, 32, 64);
        s += xp0;

        // tanh(s) = 1 - 2/(e^{2s}+1); overflow-safe without clamps
        // (e=inf -> hn=1; e=0 -> hn=-1)
        float e  = __expf(2.0f * s);
        float hn = 1.0f - __fdividef(2.0f, e + 1.0f);

        if (q == 0) {
            h_lds[(t & 1) ^ 1][(j >> 6) * 68 + (j & 63)] = hn;
            base[(size_t)t * HH + j] = hn;     // overwrite xproj with hidden
        }
        __syncthreads();
        xp0 = xp1;
        xp1 = xp2;
    }
}

// ---------------------------------------------------------------------------
extern "C" void kernel_launch(void* const* d_in, const int* in_sizes, int n_in,
                              void* d_out, int out_size, void* d_ws, size_t ws_size,
                              hipStream_t stream) {
    const float* x    = (const float*)d_in[0];
    const float* W_ih = (const float*)d_in[1];
    const float* W_hh = (const float*)d_in[2];
    const float* b_ih = (const float*)d_in[3];
    const float* b_hh = (const float*)d_in[4];
    const float* W_fc = (const float*)d_in[5];
    const float* b_fc = (const float*)d_in[6];

    float* out_fc  = (float*)d_out;                          // [B][S][O]
    float* hidden  = (float*)d_out + (size_t)BB * SS * OO;   // [B][S][H]

    float* wihT  = (float*)d_ws;                 // [I][H]
    float* wfcT  = wihT + II * HH;               // [H][O]
    float* biasc = wfcT + HH * OO;               // [H]

    const long NR = (long)BB * SS;               // 131072 rows

    prep_kernel<<<128, 256, 0, stream>>>(W_ih, b_ih, b_hh, W_fc, wihT, wfcT, biasc);
    gemm_rk<II, HH, 64><<<NR / 64, 256, 0, stream>>>(x, wihT, biasc, hidden);
    rnn_scan<<<BB, 1024, 0, stream>>>(W_hh, hidden);
    gemm_rk<HH, OO, 128><<<NR / 128, 256, 0, stream>>>(hidden, wfcT, b_fc, out_fc);
}

// Round 7
// 1808.071 us; speedup vs baseline: 1.0219x; 1.0219x over previous
//
#include <hip/hip_runtime.h>

#define BB 64
#define SS 2048
#define II 128
#define HH 256
#define OO 128

// ---------------------------------------------------------------------------
// Prep: transpose W_ih -> [I][H], W_fc -> [H][O], combine biases.
// ---------------------------------------------------------------------------
__global__ void prep_kernel(const float* __restrict__ W_ih, const float* __restrict__ b_ih,
                            const float* __restrict__ b_hh, const float* __restrict__ W_fc,
                            float* __restrict__ wihT, float* __restrict__ wfcT,
                            float* __restrict__ biasc) {
    int idx = blockIdx.x * 256 + threadIdx.x;
    if (idx < HH * II) {            // W_ih [H][I] -> wihT [I][H]
        int j = idx / II, k = idx % II;
        wihT[k * HH + j] = W_ih[idx];
    }
    if (idx < OO * HH) {            // W_fc [O][H] -> wfcT [H][O]
        int j = idx / HH, k = idx % HH;
        wfcT[k * OO + j] = W_fc[idx];
    }
    if (idx < HH) biasc[idx] = b_ih[idx] + b_hh[idx];
}

// ---------------------------------------------------------------------------
// Generic row-major GEMM: C[r][j] = sum_k A[r][k] * Wt[k][j] + bias[j]
// 256 threads, 8x8 micro-tile per thread. (unchanged — scan dominates)
// ---------------------------------------------------------------------------
template<int KD, int JD, int RT>
__global__ __launch_bounds__(256, 2)
void gemm_rk(const float* __restrict__ A, const float* __restrict__ Wt,
             const float* __restrict__ bias, float* __restrict__ C) {
    constexpr int KT = 64;
    constexpr int TJ = JD / 8;      // threads along j
    constexpr int TR = RT / 8;      // threads along r  (TJ*TR == 256)
    static_assert(TJ * TR == 256, "bad tiling");

    __shared__ __align__(16) float a_lds[RT][KT];
    __shared__ __align__(16) float w_lds[KT][JD];

    const int tid = threadIdx.x;
    const int tj = tid % TJ;
    const int tr = tid / TJ;
    const long r0 = (long)blockIdx.x * RT;

    float acc[8][8];
#pragma unroll
    for (int r = 0; r < 8; ++r)
#pragma unroll
        for (int j = 0; j < 8; ++j) acc[r][j] = 0.0f;

    for (int kt = 0; kt < KD; kt += KT) {
        {
            constexpr int NF4 = RT * KT / 4;
#pragma unroll
            for (int f = 0; f < NF4 / 256; ++f) {
                int fl = f * 256 + tid;
                int rr = fl / (KT / 4), kk4 = fl % (KT / 4);
                *(float4*)&a_lds[rr][kk4 * 4] =
                    *(const float4*)&A[(r0 + rr) * KD + kt + kk4 * 4];
            }
        }
        {
            constexpr int NF4 = KT * JD / 4;
#pragma unroll
            for (int f = 0; f < NF4 / 256; ++f) {
                int fl = f * 256 + tid;
                int kk = fl / (JD / 4), jj4 = fl % (JD / 4);
                *(float4*)&w_lds[kk][jj4 * 4] =
                    *(const float4*)&Wt[(long)(kt + kk) * JD + jj4 * 4];
            }
        }
        __syncthreads();

#pragma unroll 4
        for (int k4 = 0; k4 < KT; k4 += 4) {
            float4 xv[8];
#pragma unroll
            for (int r = 0; r < 8; ++r)
                xv[r] = *(const float4*)&a_lds[tr * 8 + r][k4];
#pragma unroll
            for (int i = 0; i < 4; ++i) {
                float4 wa = *(const float4*)&w_lds[k4 + i][tj * 8];
                float4 wb = *(const float4*)&w_lds[k4 + i][tj * 8 + 4];
#pragma unroll
                for (int r = 0; r < 8; ++r) {
                    float xs = (i == 0) ? xv[r].x : (i == 1) ? xv[r].y
                             : (i == 2) ? xv[r].z : xv[r].w;
                    acc[r][0] = fmaf(xs, wa.x, acc[r][0]);
                    acc[r][1] = fmaf(xs, wa.y, acc[r][1]);
                    acc[r][2] = fmaf(xs, wa.z, acc[r][2]);
                    acc[r][3] = fmaf(xs, wa.w, acc[r][3]);
                    acc[r][4] = fmaf(xs, wb.x, acc[r][4]);
                    acc[r][5] = fmaf(xs, wb.y, acc[r][5]);
                    acc[r][6] = fmaf(xs, wb.z, acc[r][6]);
                    acc[r][7] = fmaf(xs, wb.w, acc[r][7]);
                }
            }
        }
        __syncthreads();
    }

    float4 b0 = *(const float4*)&bias[tj * 8];
    float4 b1 = *(const float4*)&bias[tj * 8 + 4];
#pragma unroll
    for (int r = 0; r < 8; ++r) {
        long row = r0 + tr * 8 + r;
        float4 o0, o1;
        o0.x = acc[r][0] + b0.x; o0.y = acc[r][1] + b0.y;
        o0.z = acc[r][2] + b0.z; o0.w = acc[r][3] + b0.w;
        o1.x = acc[r][4] + b1.x; o1.y = acc[r][5] + b1.y;
        o1.z = acc[r][6] + b1.z; o1.w = acc[r][7] + b1.w;
        *(float4*)&C[row * JD + tj * 8]     = o0;
        *(float4*)&C[row * JD + tj * 8 + 4] = o1;
    }
}

// ---------------------------------------------------------------------------
// Sequential scan v4: h_t = tanh(xp_t + h_{t-1} @ W_hh^T), in-place.
// 64 blocks (one per batch) x 512 threads (8 waves).
//
// KEY FIX (from v1-v3 counters): VGPR_Count was 84/84/44 against designs
// needing 128/128/64 resident weight floats -> the register allocator's
// occupancy heuristic was evicting the weights (targeting 4-8 waves/EU
// co-residency that our 64-block grid never uses), forcing per-step weight
// reload/copy (~2.5x VALU bloat, 78% active-CU VALUBusy of overhead).
// amdgpu_waves_per_eu(2,2) pins the occupancy target: budget = 256 VGPR,
// nothing to gain by shrinking -> 128 weight floats stay resident (~180 regs).
//
// Wave w owns outputs [w*32, w*32+32). Lane l: sl=l&15 -> outputs
// j0=w*32+sl*2, j0+1; q=l>>4 -> k-slice [q*64, q*64+64). 128 FMAs on 4 ILP
// chains; butterfly shfl_xor(16,32) reduces the 4 k-quarters in-wave; all
// lanes compute tanh (no branch), q==0 lanes store. h double-buffered in
// LDS, quarters staggered by 68 floats (the 4 distinct broadcast addresses
// per ds_read_b128 hit disjoint banks). ONE barrier per step.
// ---------------------------------------------------------------------------
__global__ __attribute__((amdgpu_waves_per_eu(2, 2))) __launch_bounds__(512)
void rnn_scan(const float* __restrict__ W_hh, float* __restrict__ hid) {
    const int b   = blockIdx.x;
    const int tid = threadIdx.x;
    const int w   = tid >> 6;
    const int l   = tid & 63;
    const int sl  = l & 15;
    const int q   = l >> 4;

    const int j0 = w * 32 + sl * 2;      // two outputs j0, j0+1
    const int k0 = q * 64;               // k range [k0, k0+64)

    __shared__ __align__(16) float h_lds[2][4 * 68];

    // per-thread weights: rows j0, j0+1, cols [k0, k0+64) = 128 floats
    float4 wA[16], wB[16];
#pragma unroll
    for (int i = 0; i < 16; ++i) {
        wA[i] = *(const float4*)&W_hh[(size_t)j0 * HH + k0 + i * 4];
        wB[i] = *(const float4*)&W_hh[(size_t)(j0 + 1) * HH + k0 + i * 4];
    }
    // Opaque pin: forbids rematerializing the loads later.
#pragma unroll
    for (int i = 0; i < 16; ++i) {
        asm volatile("" : "+v"(wA[i].x), "+v"(wA[i].y), "+v"(wA[i].z), "+v"(wA[i].w));
        asm volatile("" : "+v"(wB[i].x), "+v"(wB[i].y), "+v"(wB[i].z), "+v"(wB[i].w));
    }

    for (int i = tid; i < 2 * 4 * 68; i += 512) ((float*)h_lds)[i] = 0.0f;

    float* __restrict__ base = hid + (size_t)b * SS * HH;
    // xproj prefetch, depth 2; all quarter-groups load the same address
    // (coalescer broadcast), every lane keeps a copy for the tanh phase
    float2 xp0 = *(const float2*)&base[j0];
    float2 xp1 = *(const float2*)&base[HH + j0];
    __syncthreads();

#pragma unroll 1
    for (int t = 0; t < SS; ++t) {
        // prefetch xproj for t+2 (read precedes the overwrite at t)
        float2 xp2 = make_float2(0.f, 0.f);
        if (t + 2 < SS) xp2 = *(const float2*)&base[(size_t)(t + 2) * HH + j0];

        const float4* hb = (const float4*)&h_lds[t & 1][q * 68];
        float a0 = 0.f, a1 = 0.f, c0 = 0.f, c1 = 0.f;
#pragma unroll
        for (int i = 0; i < 16; i += 2) {
            float4 h0 = hb[i];
            float4 h1 = hb[i + 1];
            a0 = fmaf(h0.x, wA[i].x, a0);
            a0 = fmaf(h0.y, wA[i].y, a0);
            a0 = fmaf(h0.z, wA[i].z, a0);
            a0 = fmaf(h0.w, wA[i].w, a0);
            a1 = fmaf(h1.x, wA[i + 1].x, a1);
            a1 = fmaf(h1.y, wA[i + 1].y, a1);
            a1 = fmaf(h1.z, wA[i + 1].z, a1);
            a1 = fmaf(h1.w, wA[i + 1].w, a1);
            c0 = fmaf(h0.x, wB[i].x, c0);
            c0 = fmaf(h0.y, wB[i].y, c0);
            c0 = fmaf(h0.z, wB[i].z, c0);
            c0 = fmaf(h0.w, wB[i].w, c0);
            c1 = fmaf(h1.x, wB[i + 1].x, c1);
            c1 = fmaf(h1.y, wB[i + 1].y, c1);
            c1 = fmaf(h1.z, wB[i + 1].z, c1);
            c1 = fmaf(h1.w, wB[i + 1].w, c1);
        }
        float sA = a0 + a1;
        float sB = c0 + c1;
        // butterfly over the 4 k-quarters (lanes sl, sl+16, sl+32, sl+48);
        // afterwards ALL lanes hold the full dots for outputs j0, j0+1
        sA += __shfl_xor(sA, 16, 64);
        sA += __shfl_xor(sA, 32, 64);
        sB += __shfl_xor(sB, 16, 64);
        sB += __shfl_xor(sB, 32, 64);

        float s0 = xp0.x + sA;
        float s1 = xp0.y + sB;
        // tanh(s) = 1 - 2/(e^{2s}+1); overflow-safe without clamps
        float e0  = __expf(2.0f * s0);
        float e1  = __expf(2.0f * s1);
        float hn0 = 1.0f - __fdividef(2.0f, e0 + 1.0f);
        float hn1 = 1.0f - __fdividef(2.0f, e1 + 1.0f);

        if (q == 0) {
            *(float2*)&h_lds[(t & 1) ^ 1][(j0 >> 6) * 68 + (j0 & 63)] =
                make_float2(hn0, hn1);
            *(float2*)&base[(size_t)t * HH + j0] = make_float2(hn0, hn1);
        }
        __syncthreads();
        xp0 = xp1;
        xp1 = xp2;
    }
}

// ---------------------------------------------------------------------------
extern "C" void kernel_launch(void* const* d_in, const int* in_sizes, int n_in,
                              void* d_out, int out_size, void* d_ws, size_t ws_size,
                              hipStream_t stream) {
    const float* x    = (const float*)d_in[0];
    const float* W_ih = (const float*)d_in[1];
    const float* W_hh = (const float*)d_in[2];
    const float* b_ih = (const float*)d_in[3];
    const float* b_hh = (const float*)d_in[4];
    const float* W_fc = (const float*)d_in[5];
    const float* b_fc = (const float*)d_in[6];

    float* out_fc  = (float*)d_out;                          // [B][S][O]
    float* hidden  = (float*)d_out + (size_t)BB * SS * OO;   // [B][S][H]

    float* wihT  = (float*)d_ws;                 // [I][H]
    float* wfcT  = wihT + II * HH;               // [H][O]
    float* biasc = wfcT + HH * OO;               // [H]

    const long NR = (long)BB * SS;               // 131072 rows

    prep_kernel<<<128, 256, 0, stream>>>(W_ih, b_ih, b_hh, W_fc, wihT, wfcT, biasc);
    gemm_rk<II, HH, 64><<<NR / 64, 256, 0, stream>>>(x, wihT, biasc, hidden);
    rnn_scan<<<BB, 512, 0, stream>>>(W_hh, hidden);
    gemm_rk<HH, OO, 128><<<NR / 128, 256, 0, stream>>>(hidden, wfcT, b_fc, out_fc);
}

// Round 8
// 1581.865 us; speedup vs baseline: 1.1680x; 1.1430x over previous
//
#include <hip/hip_runtime.h>

#define BB 64
#define SS 2048
#define II 128
#define HH 256
#define OO 128

typedef _Float16 h2_t __attribute__((ext_vector_type(2)));

__device__ __forceinline__ h2_t u2h(unsigned u) {
    union { unsigned u; h2_t h; } c; c.u = u; return c.h;
}

#if __has_builtin(__builtin_amdgcn_fdot2)
__device__ __forceinline__ float fdot2(unsigned h, unsigned w, float acc) {
    return __builtin_amdgcn_fdot2(u2h(h), u2h(w), acc, false);
}
#else
__device__ __forceinline__ float fdot2(unsigned h, unsigned w, float acc) {
    h2_t hh = u2h(h), ww = u2h(w);
    acc = fmaf((float)hh.x, (float)ww.x, acc);
    acc = fmaf((float)hh.y, (float)ww.y, acc);
    return acc;
}
#endif

// ---------------------------------------------------------------------------
// Prep: transpose W_ih -> [I][H], W_fc -> [H][O], combine biases,
// pack W_hh into f16 pairs: whh16[j][i] = (f16 W_hh[j][2i], f16 W_hh[j][2i+1])
// ---------------------------------------------------------------------------
__global__ void prep_kernel(const float* __restrict__ W_ih, const float* __restrict__ b_ih,
                            const float* __restrict__ b_hh, const float* __restrict__ W_fc,
                            float* __restrict__ wihT, float* __restrict__ wfcT,
                            float* __restrict__ biasc, unsigned* __restrict__ whh16,
                            const float* __restrict__ W_hh) {
    int idx = blockIdx.x * 256 + threadIdx.x;
    if (idx < HH * II) {            // W_ih [H][I] -> wihT [I][H]
        int j = idx / II, k = idx % II;
        wihT[k * HH + j] = W_ih[idx];
    }
    if (idx < OO * HH) {            // W_fc [O][H] -> wfcT [H][O]
        int j = idx / HH, k = idx % HH;
        wfcT[k * OO + j] = W_fc[idx];
    }
    if (idx < HH * (HH / 2)) {      // W_hh -> packed f16 pairs [256][128]
        int j = idx / (HH / 2), i = idx % (HH / 2);
        union { h2_t h; unsigned u; } pk;
        pk.h.x = (_Float16)W_hh[j * HH + 2 * i];
        pk.h.y = (_Float16)W_hh[j * HH + 2 * i + 1];
        whh16[idx] = pk.u;
    }
    if (idx < HH) biasc[idx] = b_ih[idx] + b_hh[idx];
}

// ---------------------------------------------------------------------------
// Generic row-major GEMM: C[r][j] = sum_k A[r][k] * Wt[k][j] + bias[j]
// 256 threads, 8x8 micro-tile per thread. (unchanged — scan dominates)
// ---------------------------------------------------------------------------
template<int KD, int JD, int RT>
__global__ __launch_bounds__(256, 2)
void gemm_rk(const float* __restrict__ A, const float* __restrict__ Wt,
             const float* __restrict__ bias, float* __restrict__ C) {
    constexpr int KT = 64;
    constexpr int TJ = JD / 8;      // threads along j
    constexpr int TR = RT / 8;      // threads along r  (TJ*TR == 256)
    static_assert(TJ * TR == 256, "bad tiling");

    __shared__ __align__(16) float a_lds[RT][KT];
    __shared__ __align__(16) float w_lds[KT][JD];

    const int tid = threadIdx.x;
    const int tj = tid % TJ;
    const int tr = tid / TJ;
    const long r0 = (long)blockIdx.x * RT;

    float acc[8][8];
#pragma unroll
    for (int r = 0; r < 8; ++r)
#pragma unroll
        for (int j = 0; j < 8; ++j) acc[r][j] = 0.0f;

    for (int kt = 0; kt < KD; kt += KT) {
        {
            constexpr int NF4 = RT * KT / 4;
#pragma unroll
            for (int f = 0; f < NF4 / 256; ++f) {
                int fl = f * 256 + tid;
                int rr = fl / (KT / 4), kk4 = fl % (KT / 4);
                *(float4*)&a_lds[rr][kk4 * 4] =
                    *(const float4*)&A[(r0 + rr) * KD + kt + kk4 * 4];
            }
        }
        {
            constexpr int NF4 = KT * JD / 4;
#pragma unroll
            for (int f = 0; f < NF4 / 256; ++f) {
                int fl = f * 256 + tid;
                int kk = fl / (JD / 4), jj4 = fl % (JD / 4);
                *(float4*)&w_lds[kk][jj4 * 4] =
                    *(const float4*)&Wt[(long)(kt + kk) * JD + jj4 * 4];
            }
        }
        __syncthreads();

#pragma unroll 4
        for (int k4 = 0; k4 < KT; k4 += 4) {
            float4 xv[8];
#pragma unroll
            for (int r = 0; r < 8; ++r)
                xv[r] = *(const float4*)&a_lds[tr * 8 + r][k4];
#pragma unroll
            for (int i = 0; i < 4; ++i) {
                float4 wa = *(const float4*)&w_lds[k4 + i][tj * 8];
                float4 wb = *(const float4*)&w_lds[k4 + i][tj * 8 + 4];
#pragma unroll
                for (int r = 0; r < 8; ++r) {
                    float xs = (i == 0) ? xv[r].x : (i == 1) ? xv[r].y
                             : (i == 2) ? xv[r].z : xv[r].w;
                    acc[r][0] = fmaf(xs, wa.x, acc[r][0]);
                    acc[r][1] = fmaf(xs, wa.y, acc[r][1]);
                    acc[r][2] = fmaf(xs, wa.z, acc[r][2]);
                    acc[r][3] = fmaf(xs, wa.w, acc[r][3]);
                    acc[r][4] = fmaf(xs, wb.x, acc[r][4]);
                    acc[r][5] = fmaf(xs, wb.y, acc[r][5]);
                    acc[r][6] = fmaf(xs, wb.z, acc[r][6]);
                    acc[r][7] = fmaf(xs, wb.w, acc[r][7]);
                }
            }
        }
        __syncthreads();
    }

    float4 b0 = *(const float4*)&bias[tj * 8];
    float4 b1 = *(const float4*)&bias[tj * 8 + 4];
#pragma unroll
    for (int r = 0; r < 8; ++r) {
        long row = r0 + tr * 8 + r;
        float4 o0, o1;
        o0.x = acc[r][0] + b0.x; o0.y = acc[r][1] + b0.y;
        o0.z = acc[r][2] + b0.z; o0.w = acc[r][3] + b0.w;
        o1.x = acc[r][4] + b1.x; o1.y = acc[r][5] + b1.y;
        o1.z = acc[r][6] + b1.z; o1.w = acc[r][7] + b1.w;
        *(float4*)&C[row * JD + tj * 8]     = o0;
        *(float4*)&C[row * JD + tj * 8 + 4] = o1;
    }
}

// ---------------------------------------------------------------------------
// Sequential scan v5: h_t = tanh(xp_t + h_{t-1} @ W_hh^T), in-place, f16 dot.
// 64 blocks (one per batch) x 512 threads (8 waves).
//
// v1-v4 lesson (counters): two stacked costs kept the step at ~1600 cyc:
//  (a) weights demoted to AGPRs with a v_accvgpr_read per use (~512 cyc/SIMD);
//  (b) LDS return BW: each thread receives its fp32 k-slice each step ->
//      512thr x 256B = 128 KB/CU/step / ~128 B/cyc ~ 1024 cyc.
// v5 stores W_hh and the recurrent h as f16 pairs and accumulates fp32 via
// v_dot2_f32_f16: halves LDS bytes (64 KB/step), halves MAC issue (64 dot2
// per thread), and halves weight registers (64 VGPRs packed) so the
// allocator can keep them resident inside the 128-VGPR tier.
//
// Wave w owns outputs [w*32, w*32+32). Lane l: sl=l&15 -> outputs
// j0=w*32+sl*2, j0+1; q=l>>4 -> k-quarter (32 packed words). Butterfly
// shfl_xor(16,32) reduces quarters in-wave; all lanes compute tanh;
// q==0 lanes store (f16x2 to LDS, fp32 to global). h double-buffered,
// quarters staggered by 36 words (16B-aligned, +4 bank offset per quarter).
// ONE barrier per step.
// ---------------------------------------------------------------------------
__global__ __attribute__((amdgpu_waves_per_eu(2, 2))) __launch_bounds__(512)
void rnn_scan(const unsigned* __restrict__ whh16, float* __restrict__ hid) {
    const int b   = blockIdx.x;
    const int tid = threadIdx.x;
    const int w   = tid >> 6;
    const int l   = tid & 63;
    const int sl  = l & 15;
    const int q   = l >> 4;

    const int j0 = w * 32 + sl * 2;      // two outputs j0, j0+1

    __shared__ __align__(16) unsigned h16[2][4 * 36];

    // packed weights: rows j0, j0+1, quarter q -> 32 words (64 f16) per row
    uint4 wA[8], wB[8];
#pragma unroll
    for (int i = 0; i < 8; ++i) {
        wA[i] = *(const uint4*)&whh16[(size_t)j0 * (HH / 2) + q * 32 + i * 4];
        wB[i] = *(const uint4*)&whh16[(size_t)(j0 + 1) * (HH / 2) + q * 32 + i * 4];
    }

    for (int i = tid; i < 2 * 4 * 36; i += 512) ((unsigned*)h16)[i] = 0u;

    float* __restrict__ base = hid + (size_t)b * SS * HH;
    float2 xp0 = *(const float2*)&base[j0];
    float2 xp1 = *(const float2*)&base[HH + j0];
    __syncthreads();

#pragma unroll 1
    for (int t = 0; t < SS; ++t) {
        // prefetch xproj for t+2 (read precedes the overwrite at t)
        float2 xp2 = make_float2(0.f, 0.f);
        if (t + 2 < SS) xp2 = *(const float2*)&base[(size_t)(t + 2) * HH + j0];

        const uint4* hb = (const uint4*)&h16[t & 1][q * 36];
        float aA0 = 0.f, aA1 = 0.f, aB0 = 0.f, aB1 = 0.f;
#pragma unroll
        for (int i = 0; i < 8; ++i) {
            uint4 hv = hb[i];
            aA0 = fdot2(hv.x, wA[i].x, aA0);
            aA1 = fdot2(hv.y, wA[i].y, aA1);
            aA0 = fdot2(hv.z, wA[i].z, aA0);
            aA1 = fdot2(hv.w, wA[i].w, aA1);
            aB0 = fdot2(hv.x, wB[i].x, aB0);
            aB1 = fdot2(hv.y, wB[i].y, aB1);
            aB0 = fdot2(hv.z, wB[i].z, aB0);
            aB1 = fdot2(hv.w, wB[i].w, aB1);
        }
        float sA = aA0 + aA1;
        float sB = aB0 + aB1;
        // butterfly over the 4 k-quarters (lanes sl, sl+16, sl+32, sl+48)
        sA += __shfl_xor(sA, 16, 64);
        sA += __shfl_xor(sA, 32, 64);
        sB += __shfl_xor(sB, 16, 64);
        sB += __shfl_xor(sB, 32, 64);

        float s0 = xp0.x + sA;
        float s1 = xp0.y + sB;
        // tanh(s) = 1 - 2/(e^{2s}+1); overflow-safe without clamps
        float e0  = __expf(2.0f * s0);
        float e1  = __expf(2.0f * s1);
        float hn0 = 1.0f - __fdividef(2.0f, e0 + 1.0f);
        float hn1 = 1.0f - __fdividef(2.0f, e1 + 1.0f);

        if (q == 0) {
            union { h2_t h; unsigned u; } pk;
            pk.h.x = (_Float16)hn0;
            pk.h.y = (_Float16)hn1;
            const int W = j0 >> 1;
            h16[(t & 1) ^ 1][(W >> 5) * 36 + (W & 31)] = pk.u;
            *(float2*)&base[(size_t)t * HH + j0] = make_float2(hn0, hn1);
        }
        __syncthreads();
        xp0 = xp1;
        xp1 = xp2;
    }
}

// ---------------------------------------------------------------------------
extern "C" void kernel_launch(void* const* d_in, const int* in_sizes, int n_in,
                              void* d_out, int out_size, void* d_ws, size_t ws_size,
                              hipStream_t stream) {
    const float* x    = (const float*)d_in[0];
    const float* W_ih = (const float*)d_in[1];
    const float* W_hh = (const float*)d_in[2];
    const float* b_ih = (const float*)d_in[3];
    const float* b_hh = (const float*)d_in[4];
    const float* W_fc = (const float*)d_in[5];
    const float* b_fc = (const float*)d_in[6];

    float* out_fc  = (float*)d_out;                          // [B][S][O]
    float* hidden  = (float*)d_out + (size_t)BB * SS * OO;   // [B][S][H]

    float*    wihT  = (float*)d_ws;                  // [I][H]  32768 f
    float*    wfcT  = wihT + II * HH;                // [H][O]  32768 f
    float*    biasc = wfcT + HH * OO;                // [H]       256 f
    unsigned* whh16 = (unsigned*)(biasc + HH);       // [H][H/2] 32768 u32

    const long NR = (long)BB * SS;                   // 131072 rows

    prep_kernel<<<128, 256, 0, stream>>>(W_ih, b_ih, b_hh, W_fc,
                                         wihT, wfcT, biasc, whh16, W_hh);
    gemm_rk<II, HH, 64><<<NR / 64, 256, 0, stream>>>(x, wihT, biasc, hidden);
    rnn_scan<<<BB, 512, 0, stream>>>(whh16, hidden);
    gemm_rk<HH, OO, 128><<<NR / 128, 256, 0, stream>>>(hidden, wfcT, b_fc, out_fc);
}